// Round 11
// baseline (45.875 us; speedup 1.0000x reference)
//
#include <hip/hip_runtime.h>
#include <hip/hip_bf16.h>
#include <stdint.h>

#define IMG   224
#define OUTD  256
#define BATCH 256
#define JD    25
#define TD    64
#define MIDJ  12
#define BOXR  20
#define MAXEV 1536   // >= 224 x * 5 runs max (40-wide y-intervals => <=5 disjoint)

typedef float vfloat4 __attribute__((ext_vector_type(4)));

// workspace layout (bytes)
//   P      : bf16 [224][225][256]   = 25,804,800
//   evlist : u32  [256][1536]       =  1,572,864  (<=1120 used per batch)
//   evcnt  : u32  [256]             =      1,024
#define OFF_EV   25804800u
#define OFF_EVC  27377664u

// NOTE (r4/r5): NO device-scope fences / coop grid sync inside kernels — on
// gfx950 an agent-scope release forces an L2 writeback per issuing block
// (per-XCD L2s non-coherent); cost 70-300us. Kernel boundaries give the same
// visibility with one amortized flush. (r8/r9): per-dispatch acquire also
// INVALIDATES L2, so cross-kernel L2 reuse of P is impossible — endpoint
// reads come from L3 and sit at the L3 traffic floor once >=19KB/CU of loads
// are in flight (Little's law). (r10): wpref prefers 64-o/512t big blocks
// over 32-o/256t high-occupancy ones (fewer scheduling rounds, wider stores).

// ======= KA: fused wpref (blocks 0..895, 512t) + boxes/events (896..1151) ===
__global__ void KA(const float* __restrict__ W, __hip_bfloat16* __restrict__ P,
                   const float* __restrict__ skel, uint32_t* __restrict__ evlist,
                   uint32_t* __restrict__ evcnt) {
    const int id  = blockIdx.x;
    const int tid = threadIdx.x;        // 0..511

    __shared__ float lds[64][225];      // wpref: [o_local][y]
    __shared__ float carry[8][64];
    __shared__ int s_px[JD], s_ylo[JD], s_yhi[JD];
    __shared__ uint32_t s_n[IMG];

    if (id < 896) {
        // ---------------- wpref (r9-verified config) ----------------
        const int xcd = id & 7;
        const int r   = id >> 3;        // 0..111
        const int oc  = r & 3;
        const int q   = r >> 2;         // 0..27
        const int xi  = q % 14;
        const int hi8 = q / 14;         // 0..1
        const int x   = (hi8 * 8 + xcd) * 14 + xi;
        const int o0  = oc * 64;

        // vfloat4 nontemporal loads: 64 rows x 56 float4; 3584/512 = 7/thread
        #pragma unroll
        for (int it = 0; it < 7; ++it) {
            const int k  = it * 512 + tid;
            const int rr = k / 56;
            const int c  = k - rr * 56;
            const vfloat4 v = __builtin_nontemporal_load(
                (const vfloat4*)&W[(size_t)(o0 + rr) * (IMG * IMG) + (size_t)x * IMG + c * 4]);
            lds[rr][c * 4 + 0] = v.x;
            lds[rr][c * 4 + 1] = v.y;
            lds[rr][c * 4 + 2] = v.z;
            lds[rr][c * 4 + 3] = v.w;
        }
        __syncthreads();

        const int ol  = tid & 63;       // o_local 0..63
        const int seg = tid >> 6;       // 0..7, owns y in [seg*28, seg*28+28)
        const int y0  = seg * 28;

        // register-resident scan: each LDS element read once
        float rv[28];
        #pragma unroll
        for (int i = 0; i < 28; ++i) rv[i] = lds[ol][y0 + i];

        float ssum = 0.0f;
        #pragma unroll
        for (int i = 0; i < 28; ++i) ssum += rv[i];
        carry[seg][ol] = ssum;
        __syncthreads();

        float s = 0.0f;
        for (int s2 = 0; s2 < seg; ++s2) s += carry[s2][ol];

        __hip_bfloat16* p = P + ((size_t)x * 225) * 256 + o0 + ol;
        if (seg == 0) p[0] = __float2bfloat16(0.0f);
        #pragma unroll
        for (int i = 0; i < 28; ++i) {
            s += rv[i];
            p[(size_t)(y0 + i + 1) * 256] = __float2bfloat16(s);  // 128B/wave
        }
        return;
    }

    // ---------------- boxes/events (one block per batch, 512t) --------------
    const int b = id - 896;
    const int wave = tid >> 6;          // 0..7
    const int t = tid & 63;

    const float* sb = skel + (size_t)b * JD * TD * 3;
    const float mx = sb[(MIDJ * TD + t) * 3 + 0];
    const float my = sb[(MIDJ * TD + t) * 3 + 1];
    const float mz = sb[(MIDJ * TD + t) * 3 + 2];

    for (int j = wave; j < JD; j += 8) {
        const float ax = sb[(j * TD + t) * 3 + 0];
        const float ay = sb[(j * TD + t) * 3 + 1];
        const float az = sb[(j * TD + t) * 3 + 2];
        const float dx = ax - mx, dy = ay - my, dz = az - mz;
        // match numpy: no fma contraction, left-to-right adds, IEEE sqrt
        const float d2 = __fadd_rn(__fadd_rn(__fmul_rn(dx, dx), __fmul_rn(dy, dy)),
                                   __fmul_rn(dz, dz));
        float bd = sqrtf(d2);
        int   bi = t;
        #pragma unroll
        for (int off = 1; off < 64; off <<= 1) {
            const float od = __shfl_xor(bd, off);
            const int   oi = __shfl_xor(bi, off);
            if (od > bd || (od == bd && oi < bi)) { bd = od; bi = oi; }
        }
        if (t == 0) {
            const float ptx = sb[(j * TD + bi) * 3 + 0];
            const float pty = sb[(j * TD + bi) * 3 + 1];
            const int px = (int)(ptx * 224.0f);
            const int py = (int)(pty * 224.0f);
            s_px[j]  = px;
            s_ylo[j] = (py < BOXR) ? 0 : (py - BOXR);
            s_yhi[j] = (py > IMG - BOXR) ? IMG : (py + BOXR);
        }
    }
    __syncthreads();

    const int x = tid;
    unsigned long long m0 = 0, m1 = 0, m2 = 0, m3 = 0;
    uint32_t n = 0;
    if (x < IMG) {
        for (int j = 0; j < JD; ++j) {
            if (j == MIDJ) continue;
            const int px = s_px[j];
            if (x >= px - BOXR && x < px + BOXR) {
                const int lo = s_ylo[j], hi = s_yhi[j];
                auto setw = [&](unsigned long long& mw, int wbase) {
                    int l = lo - wbase; int h = hi - wbase;
                    l = l < 0 ? 0 : l; h = h > 64 ? 64 : h;
                    if (l < h) {
                        unsigned long long msk =
                            (h - l == 64) ? ~0ull : ((((1ull << (h - l)) - 1ull)) << l);
                        mw |= msk;
                    }
                };
                setw(m0, 0); setw(m1, 64); setw(m2, 128); setw(m3, 192);
            }
        }
        // run count = rising edges of the 224-bit mask
        const unsigned long long e0 = m0 & ~(m0 << 1);
        const unsigned long long e1 = m1 & ~((m1 << 1) | (m0 >> 63));
        const unsigned long long e2 = m2 & ~((m2 << 1) | (m1 >> 63));
        const unsigned long long e3 = m3 & ~((m3 << 1) | (m2 >> 63));
        n = (uint32_t)(__popcll(e0) + __popcll(e1) + __popcll(e2) + __popcll(e3));
        s_n[x] = n;
    }
    __syncthreads();
    if (x >= IMG) return;

    // per-batch prefix offset (224-iter LDS loop, trivial ALU)
    uint32_t off = 0;
    for (int i = 0; i < x; ++i) off += s_n[i];
    if (x == IMG - 1) evcnt[b] = off + n;

    // emit events: ev = x | (start<<8) | (end<<16)   (all fit in 8 bits; end<=224)
    uint32_t* evs = evlist + (size_t)b * MAXEV + off;
    int k = 0, start = -1;
    auto scanw = [&](unsigned long long bits, int wbase) {
        int pos = 0;
        while (pos < 64) {
            if (start < 0) {
                const unsigned long long tt = bits >> pos;
                if (!tt) return;
                pos += __builtin_ctzll(tt);
                start = wbase + pos;
            } else {
                const unsigned long long tt = (~bits) >> pos;
                if (!tt) return;
                pos += __builtin_ctzll(tt);
                evs[k] = (uint32_t)x | ((uint32_t)start << 8)
                                     | ((uint32_t)(wbase + pos) << 16);
                ++k; start = -1;
            }
        }
    };
    scanw(m0, 0); scanw(m1, 64); scanw(m2, 128); scanw(m3, 192);
    if (start >= 0) { evs[k] = (uint32_t)x | ((uint32_t)start << 8) | (224u << 16); }
}

// ====== KB: per-batch accum + fused final (no part buffer, no 3rd kernel) ====
// One block per batch: 1024 threads = 8 groups x 128 lanes. Group g handles a
// contiguous chunk of the batch's events (fixed split -> deterministic), then
// LDS cross-group reduce in fixed order, then out = rgb*(bias+sum) directly.
// No cross-block dependency -> no fences (r4/r5 lesson).
__global__ void KB(const uint32_t* __restrict__ evlist,
                   const uint32_t* __restrict__ evcnt,
                   const uint32_t* __restrict__ P32,   // P viewed as bf16x2
                   const float* __restrict__ rgb, const float* __restrict__ bias,
                   float* __restrict__ out) {
    const int b   = blockIdx.x;
    const int tid = threadIdx.x;        // 0..1023
    const int g   = tid >> 7;           // 0..7
    const int l   = tid & 127;          // lane-column: outputs 2l, 2l+1

    __shared__ uint32_t slist[MAXEV];
    __shared__ float sLo[8][128];
    __shared__ float sHi[8][128];

    const uint32_t cntv = evcnt[b];
    slist[tid] = evlist[(size_t)b * MAXEV + tid];
    if (tid < MAXEV - 1024) slist[1024 + tid] = evlist[(size_t)b * MAXEV + 1024 + tid];
    __syncthreads();

    const int total = (int)cntv;
    const int chunk = (total + 7) >> 3;
    const int i0 = g * chunk;
    const int i1 = min(total, i0 + chunk);

    const uint32_t* Pb = P32 + l;
    float aLo[8] = {0.f,0.f,0.f,0.f,0.f,0.f,0.f,0.f};
    float aHi[8] = {0.f,0.f,0.f,0.f,0.f,0.f,0.f,0.f};
    int i = i0;
    for (; i + 8 <= i1; i += 8) {
        uint32_t ev[8], va[8], vc[8];
        #pragma unroll
        for (int u = 0; u < 8; ++u) ev[u] = slist[i + u];
        #pragma unroll
        for (int u = 0; u < 8; ++u) {
            const uint32_t* p = Pb + (size_t)(ev[u] & 255u) * (225 * 128);
            va[u] = p[(size_t)((ev[u] >> 8) & 255u) * 128];
            vc[u] = p[(size_t)((ev[u] >> 16) & 255u) * 128];
        }
        #pragma unroll
        for (int u = 0; u < 8; ++u) {
            aLo[u] += __uint_as_float(vc[u] << 16) - __uint_as_float(va[u] << 16);
            aHi[u] += __uint_as_float(vc[u] & 0xffff0000u) - __uint_as_float(va[u] & 0xffff0000u);
        }
    }
    for (; i < i1; ++i) {
        const uint32_t e0 = slist[i];
        const uint32_t* p0 = Pb + (size_t)(e0 & 255u) * (225 * 128);
        const uint32_t va0 = p0[(size_t)((e0 >> 8) & 255u) * 128];
        const uint32_t vc0 = p0[(size_t)((e0 >> 16) & 255u) * 128];
        aLo[0] += __uint_as_float(vc0 << 16) - __uint_as_float(va0 << 16);
        aHi[0] += __uint_as_float(vc0 & 0xffff0000u) - __uint_as_float(va0 & 0xffff0000u);
    }

    sLo[g][l] = ((aLo[0] + aLo[1]) + (aLo[2] + aLo[3]))
              + ((aLo[4] + aLo[5]) + (aLo[6] + aLo[7]));
    sHi[g][l] = ((aHi[0] + aHi[1]) + (aHi[2] + aHi[3]))
              + ((aHi[4] + aHi[5]) + (aHi[6] + aHi[7]));
    __syncthreads();

    if (tid < 128) {
        const float lo = ((sLo[0][tid] + sLo[1][tid]) + (sLo[2][tid] + sLo[3][tid]))
                       + ((sLo[4][tid] + sLo[5][tid]) + (sLo[6][tid] + sLo[7][tid]));
        const float hi = ((sHi[0][tid] + sHi[1][tid]) + (sHi[2][tid] + sHi[3][tid]))
                       + ((sHi[4][tid] + sHi[5][tid]) + (sHi[6][tid] + sHi[7][tid]));
        const size_t o = (size_t)b * 256 + 2 * tid;
        out[o]     = rgb[o]     * (bias[2 * tid]     + lo);
        out[o + 1] = rgb[o + 1] * (bias[2 * tid + 1] + hi);
    }
}

extern "C" void kernel_launch(void* const* d_in, const int* in_sizes, int n_in,
                              void* d_out, int out_size, void* d_ws, size_t ws_size,
                              hipStream_t stream) {
    const float* rgb  = (const float*)d_in[0];
    const float* skel = (const float*)d_in[1];
    const float* W    = (const float*)d_in[2];
    const float* bias = (const float*)d_in[3];
    float* out = (float*)d_out;

    uint8_t* ws = (uint8_t*)d_ws;
    __hip_bfloat16* P = (__hip_bfloat16*)(ws);
    uint32_t* evlist = (uint32_t*)(ws + OFF_EV);
    uint32_t* evcnt  = (uint32_t*)(ws + OFF_EVC);

    KA<<<dim3(1152), dim3(512), 0, stream>>>(W, P, skel, evlist, evcnt);
    KB<<<dim3(BATCH), dim3(1024), 0, stream>>>(evlist, evcnt, (const uint32_t*)P,
                                               rgb, bias, out);
}

// Round 12
// 40.111 us; speedup vs baseline: 1.1437x; 1.1437x over previous
//
#include <hip/hip_runtime.h>
#include <hip/hip_bf16.h>
#include <stdint.h>

#define IMG   224
#define OUTD  256
#define BATCH 256
#define JD    25
#define TD    64
#define MIDJ  12
#define BOXR  20
#define NSL   16           // x-slices of 14
#define SLW   14

typedef float vfloat4 __attribute__((ext_vector_type(4)));

// workspace layout (bytes)
//   P      : bf16 [224][225][256]   = 25,804,800
//   evlist : u32  [256*16][256]     =  4,194,304  (<=168 used per (b,slice))
//   evcnt  : u32  [256*16]          =     16,384
//   part   : f32  [256][16][256]    =  4,194,304
#define OFF_EV   25804800u
#define OFF_EVC  29999104u
#define OFF_PART 30015488u

// NOTE (r4/r5): NO device-scope fences / coop grid sync inside kernels — on
// gfx950 an agent-scope release forces an L2 writeback per issuing block
// (per-XCD L2s non-coherent); cost 70-300us. Kernel boundaries give the same
// visibility with one amortized flush. (r8/r9): per-dispatch acquire also
// INVALIDATES L2, so cross-kernel L2 reuse of P is impossible — k_accum's
// endpoint reads are cold-from-L3 then L2-hit within the dispatch via the
// slice->XCD mapping (blockIdx%8 round-robin, slices k & k+8 = 3.2MB per L2).
// (r10): wpref prefers 64-o/512t big blocks over 32-o/256t high-occupancy.
// (r11): per-batch mega-block fusion loses L2 locality + occupancy; keep 3
// kernels with the r9 shapes.

// ======= KA: fused wpref (blocks 0..895, 512t) + boxes/events (896..1151) ===
__global__ void KA(const float* __restrict__ W, __hip_bfloat16* __restrict__ P,
                   const float* __restrict__ skel, uint32_t* __restrict__ evlist,
                   uint32_t* __restrict__ evcnt) {
    const int id  = blockIdx.x;
    const int tid = threadIdx.x;        // 0..511

    __shared__ float lds[64][225];      // wpref: [o_local][y]
    __shared__ float carry[8][64];
    __shared__ int s_px[JD], s_ylo[JD], s_yhi[JD];
    __shared__ uint32_t s_n[IMG];

    if (id < 896) {
        // ---------------- wpref (r9-verified config) ----------------
        const int xcd = id & 7;
        const int r   = id >> 3;        // 0..111
        const int oc  = r & 3;
        const int q   = r >> 2;         // 0..27
        const int xi  = q % 14;
        const int hi8 = q / 14;         // 0..1
        const int x   = (hi8 * 8 + xcd) * SLW + xi;   // (x/14)%8 == id%8
        const int o0  = oc * 64;

        // vfloat4 nontemporal loads: 64 rows x 56 float4; 3584/512 = 7/thread
        #pragma unroll
        for (int it = 0; it < 7; ++it) {
            const int k  = it * 512 + tid;
            const int rr = k / 56;
            const int c  = k - rr * 56;
            const vfloat4 v = __builtin_nontemporal_load(
                (const vfloat4*)&W[(size_t)(o0 + rr) * (IMG * IMG) + (size_t)x * IMG + c * 4]);
            lds[rr][c * 4 + 0] = v.x;
            lds[rr][c * 4 + 1] = v.y;
            lds[rr][c * 4 + 2] = v.z;
            lds[rr][c * 4 + 3] = v.w;
        }
        __syncthreads();

        const int ol  = tid & 63;       // o_local 0..63
        const int seg = tid >> 6;       // 0..7, owns y in [seg*28, seg*28+28)
        const int y0  = seg * 28;

        // register-resident scan: each LDS element read once
        float rv[28];
        #pragma unroll
        for (int i = 0; i < 28; ++i) rv[i] = lds[ol][y0 + i];

        float ssum = 0.0f;
        #pragma unroll
        for (int i = 0; i < 28; ++i) ssum += rv[i];
        carry[seg][ol] = ssum;
        __syncthreads();

        float s = 0.0f;
        for (int s2 = 0; s2 < seg; ++s2) s += carry[s2][ol];

        __hip_bfloat16* p = P + ((size_t)x * 225) * 256 + o0 + ol;
        if (seg == 0) p[0] = __float2bfloat16(0.0f);
        #pragma unroll
        for (int i = 0; i < 28; ++i) {
            s += rv[i];
            p[(size_t)(y0 + i + 1) * 256] = __float2bfloat16(s);  // 128B/wave
        }
        return;
    }

    // ---------------- boxes/events (one block per batch, 512t) --------------
    const int b = id - 896;
    const int wave = tid >> 6;          // 0..7
    const int t = tid & 63;

    const float* sb = skel + (size_t)b * JD * TD * 3;
    const float mx = sb[(MIDJ * TD + t) * 3 + 0];
    const float my = sb[(MIDJ * TD + t) * 3 + 1];
    const float mz = sb[(MIDJ * TD + t) * 3 + 2];

    for (int j = wave; j < JD; j += 8) {
        const float ax = sb[(j * TD + t) * 3 + 0];
        const float ay = sb[(j * TD + t) * 3 + 1];
        const float az = sb[(j * TD + t) * 3 + 2];
        const float dx = ax - mx, dy = ay - my, dz = az - mz;
        // match numpy: no fma contraction, left-to-right adds, IEEE sqrt
        const float d2 = __fadd_rn(__fadd_rn(__fmul_rn(dx, dx), __fmul_rn(dy, dy)),
                                   __fmul_rn(dz, dz));
        float bd = sqrtf(d2);
        int   bi = t;
        #pragma unroll
        for (int off = 1; off < 64; off <<= 1) {
            const float od = __shfl_xor(bd, off);
            const int   oi = __shfl_xor(bi, off);
            if (od > bd || (od == bd && oi < bi)) { bd = od; bi = oi; }
        }
        if (t == 0) {
            const float ptx = sb[(j * TD + bi) * 3 + 0];
            const float pty = sb[(j * TD + bi) * 3 + 1];
            const int px = (int)(ptx * 224.0f);
            const int py = (int)(pty * 224.0f);
            s_px[j]  = px;
            s_ylo[j] = (py < BOXR) ? 0 : (py - BOXR);
            s_yhi[j] = (py > IMG - BOXR) ? IMG : (py + BOXR);
        }
    }
    __syncthreads();

    const int x = tid;
    unsigned long long m0 = 0, m1 = 0, m2 = 0, m3 = 0;
    uint32_t n = 0;
    if (x < IMG) {
        for (int j = 0; j < JD; ++j) {
            if (j == MIDJ) continue;
            const int px = s_px[j];
            if (x >= px - BOXR && x < px + BOXR) {
                const int lo = s_ylo[j], hi = s_yhi[j];
                auto setw = [&](unsigned long long& mw, int wbase) {
                    int l = lo - wbase; int h = hi - wbase;
                    l = l < 0 ? 0 : l; h = h > 64 ? 64 : h;
                    if (l < h) {
                        unsigned long long msk =
                            (h - l == 64) ? ~0ull : ((((1ull << (h - l)) - 1ull)) << l);
                        mw |= msk;
                    }
                };
                setw(m0, 0); setw(m1, 64); setw(m2, 128); setw(m3, 192);
            }
        }
        // run count = rising edges of the 224-bit mask
        const unsigned long long e0 = m0 & ~(m0 << 1);
        const unsigned long long e1 = m1 & ~((m1 << 1) | (m0 >> 63));
        const unsigned long long e2 = m2 & ~((m2 << 1) | (m1 >> 63));
        const unsigned long long e3 = m3 & ~((m3 << 1) | (m2 >> 63));
        n = (uint32_t)(__popcll(e0) + __popcll(e1) + __popcll(e2) + __popcll(e3));
        s_n[x] = n;
    }
    __syncthreads();
    if (x >= IMG) return;

    const int sl = x / SLW;             // slice 0..15
    const int xl = x - sl * SLW;        // 0..13
    uint32_t off = 0;
    for (int i = sl * SLW; i < x; ++i) off += s_n[i];
    if (xl == SLW - 1) evcnt[(size_t)b * NSL + sl] = off + n;

    // emit events: ev = xl | (start<<5) | (end<<13)
    uint32_t* evs = evlist + ((size_t)b * NSL + sl) * 256 + off;
    int k = 0, start = -1;
    auto scanw = [&](unsigned long long bits, int wbase) {
        int pos = 0;
        while (pos < 64) {
            if (start < 0) {
                const unsigned long long tt = bits >> pos;
                if (!tt) return;
                pos += __builtin_ctzll(tt);
                start = wbase + pos;
            } else {
                const unsigned long long tt = (~bits) >> pos;
                if (!tt) return;
                pos += __builtin_ctzll(tt);
                evs[k] = (uint32_t)xl | ((uint32_t)start << 5)
                                      | ((uint32_t)(wbase + pos) << 13);
                ++k; start = -1;
            }
        }
    };
    scanw(m0, 0); scanw(m1, 64); scanw(m2, 128); scanw(m3, 192);
    if (start >= 0) { evs[k] = (uint32_t)xl | ((uint32_t)start << 5) | (224u << 13); }
}

// ---------------- k_accum: run endpoint diffs over prefix table --------------
// L3/L2-bound, ILP-saturated (r9): 4096 blocks (16/CU, max occ), 8-way unroll.
__global__ void k_accum(const uint32_t* __restrict__ evlist,
                        const uint32_t* __restrict__ evcnt,
                        const uint32_t* __restrict__ P32,   // P viewed as bf16x2
                        float* __restrict__ part) {
    const int bs  = blockIdx.x;         // b*16 + s
    const int s   = bs & (NSL - 1);
    const int tid = threadIdx.x;        // 0..127 -> outputs 2*tid, 2*tid+1
    const int x0  = s * SLW;

    __shared__ uint32_t slist[256];

    const uint32_t cntv = evcnt[bs];                      // broadcast load
    slist[tid]       = evlist[(size_t)bs * 256 + tid];    // independent of cntv
    slist[128 + tid] = evlist[(size_t)bs * 256 + 128 + tid];
    __syncthreads();

    const int total = (int)cntv;
    const uint32_t* Pbase = P32 + (size_t)x0 * (225 * 128) + tid;

    float aLo[8] = {0.f,0.f,0.f,0.f,0.f,0.f,0.f,0.f};
    float aHi[8] = {0.f,0.f,0.f,0.f,0.f,0.f,0.f,0.f};
    int i = 0;
    for (; i + 8 <= total; i += 8) {
        uint32_t ev[8], va[8], vc[8];
        #pragma unroll
        for (int u = 0; u < 8; ++u) ev[u] = slist[i + u];
        #pragma unroll
        for (int u = 0; u < 8; ++u) {
            const uint32_t* p = Pbase + (size_t)(ev[u] & 31u) * (225 * 128);
            va[u] = p[(size_t)((ev[u] >> 5) & 255u) * 128];
            vc[u] = p[(size_t)((ev[u] >> 13) & 255u) * 128];
        }
        #pragma unroll
        for (int u = 0; u < 8; ++u) {
            aLo[u] += __uint_as_float(vc[u] << 16) - __uint_as_float(va[u] << 16);
            aHi[u] += __uint_as_float(vc[u] & 0xffff0000u) - __uint_as_float(va[u] & 0xffff0000u);
        }
    }
    for (; i < total; ++i) {
        const uint32_t e0 = slist[i];
        const uint32_t* p0 = Pbase + (size_t)(e0 & 31u) * (225 * 128);
        const uint32_t va0 = p0[(size_t)((e0 >> 5) & 255u) * 128];
        const uint32_t vc0 = p0[(size_t)((e0 >> 13) & 255u) * 128];
        aLo[0] += __uint_as_float(vc0 << 16) - __uint_as_float(va0 << 16);
        aHi[0] += __uint_as_float(vc0 & 0xffff0000u) - __uint_as_float(va0 & 0xffff0000u);
    }

    // fixed pairwise reduction order -> deterministic
    const float lo = ((aLo[0] + aLo[1]) + (aLo[2] + aLo[3]))
                   + ((aLo[4] + aLo[5]) + (aLo[6] + aLo[7]));
    const float hi = ((aHi[0] + aHi[1]) + (aHi[2] + aHi[3]))
                   + ((aHi[4] + aHi[5]) + (aHi[6] + aHi[7]));

    float* pp = part + ((size_t)bs * 256) + (size_t)tid * 2;
    pp[0] = lo;
    pp[1] = hi;
}

// ------- k_final: out = rgb * (bias + sum part), float4 over o ---------------
// 64 blocks x 256 threads; thread handles one (b, o-quad).
__global__ void k_final(const float* __restrict__ rgb, const float* __restrict__ bias,
                        const float* __restrict__ part, float* __restrict__ out) {
    const int idx = blockIdx.x * 256 + threadIdx.x;   // 0..16383
    const int b  = idx >> 6;            // 0..255
    const int oq = idx & 63;            // o-quad 0..63
    const float4 bv = *(const float4*)&bias[oq * 4];
    float m0 = bv.x, m1 = bv.y, m2 = bv.z, m3 = bv.w;
    #pragma unroll
    for (int s = 0; s < NSL; ++s) {
        const float4 pv = *(const float4*)&part[(((size_t)b * NSL + s) * 256) + oq * 4];
        m0 += pv.x; m1 += pv.y; m2 += pv.z; m3 += pv.w;
    }
    const float4 rv = *(const float4*)&rgb[(size_t)b * 256 + oq * 4];
    float4 ov;
    ov.x = rv.x * m0; ov.y = rv.y * m1; ov.z = rv.z * m2; ov.w = rv.w * m3;
    *(float4*)&out[(size_t)b * 256 + oq * 4] = ov;
}

extern "C" void kernel_launch(void* const* d_in, const int* in_sizes, int n_in,
                              void* d_out, int out_size, void* d_ws, size_t ws_size,
                              hipStream_t stream) {
    const float* rgb  = (const float*)d_in[0];
    const float* skel = (const float*)d_in[1];
    const float* W    = (const float*)d_in[2];
    const float* bias = (const float*)d_in[3];
    float* out = (float*)d_out;

    uint8_t* ws = (uint8_t*)d_ws;
    __hip_bfloat16* P = (__hip_bfloat16*)(ws);
    uint32_t* evlist = (uint32_t*)(ws + OFF_EV);
    uint32_t* evcnt  = (uint32_t*)(ws + OFF_EVC);
    float* part = (float*)(ws + OFF_PART);

    KA<<<dim3(1152), dim3(512), 0, stream>>>(W, P, skel, evlist, evcnt);
    k_accum<<<dim3(BATCH * NSL), dim3(128), 0, stream>>>(evlist, evcnt, (const uint32_t*)P, part);
    k_final<<<dim3(64), dim3(256), 0, stream>>>(rgb, bias, part, out);
}